// Round 3
// baseline (110.898 us; speedup 1.0000x reference)
//
#include <hip/hip_runtime.h>
#include <cstdint>

typedef unsigned int u32;

// ---------------------------------------------------------------------------
// Threefry-2x32 (20 rounds) — validated bit-exact vs JAX in round 1
// (jax_threefry_partitionable=True semantics).
//   split(key, n)[i]           = threefry2x32(key, (0, i))
//   random_bits(key,32,shape)e = r0 ^ r1 of threefry2x32(key, (0, e))
// ---------------------------------------------------------------------------
#define TF_R4(a,b,r1,r2,r3,r4) \
  a += b; b = (b<<r1)|(b>>(32-r1)); b ^= a; \
  a += b; b = (b<<r2)|(b>>(32-r2)); b ^= a; \
  a += b; b = (b<<r3)|(b>>(32-r3)); b ^= a; \
  a += b; b = (b<<r4)|(b>>(32-r4)); b ^= a;

__host__ __device__ inline void tf2x32(u32 k0, u32 k1, u32& x0, u32& x1) {
  const u32 k2 = k0 ^ k1 ^ 0x1BD11BDAu;
  u32 a = x0 + k0, b = x1 + k1;
  TF_R4(a,b,13,15,26,6)   a += k1; b += k2 + 1u;
  TF_R4(a,b,17,29,16,24)  a += k2; b += k0 + 2u;
  TF_R4(a,b,13,15,26,6)   a += k0; b += k1 + 3u;
  TF_R4(a,b,17,29,16,24)  a += k1; b += k2 + 4u;
  TF_R4(a,b,13,15,26,6)   a += k2; b += k0 + 5u;
  x0 = a; x1 = b;
}

__host__ __device__ inline float u01(u32 bits) {
  union { u32 u; float f; } c; c.u = (bits >> 9) | 0x3f800000u;
  return c.f - 1.0f;
}
__host__ __device__ inline u32 rbits_scalar(u32 k0, u32 k1) {
  u32 a = 0, b = 0; tf2x32(k0, k1, a, b); return a ^ b;
}

// problem constants
#define BATCH   512
#define HW      224
#define S       50176     /* 224*224 */
#define S4      12544     /* S/4 */
#define NTOT    25690112  /* 512*50176 */
#define TPB     1024      /* 16 waves */
#define NW      16
#define ITER    13        /* ceil(S4 / TPB) */

// ---------------------------------------------------------------------------
// Fused kernel, one block per sample, NO per-thread sample array (round-2
// lesson: 14xfloat4/thread forced scratch spills at the 64-VGPR cap).
// x re-reads hit L3 (103 MB < 256 MB Infinity Cache).
//   pass A (HBM): max / first-argmax / min  -> thr, apply_flag
//   pass B (L3, only if apply): bbox of prop -> erase box
//   pass C (L3 read, HBM write): out/mask; threefry only for erased elems
// ---------------------------------------------------------------------------
__global__ __launch_bounds__(TPB, 8) void k_fused(const float* __restrict__ x,
                                                  float* __restrict__ out,
                                                  float factor,
                                                  u32 ks0, u32 ks1,
                                                  u32 kn0, u32 kn1) {
  const int b    = blockIdx.x;
  const int t    = threadIdx.x;
  const int lane = t & 63, wid = t >> 6;
  const float4* __restrict__ xs = (const float4*)(x + (size_t)b * S);
  float4* __restrict__ os = (float4*)(out + (size_t)b * S);
  float4* __restrict__ ms = (float4*)(out + (size_t)NTOT + (size_t)b * S);

  __shared__ float pmax[NW]; __shared__ int pidx[NW]; __shared__ float pmin[NW];
  __shared__ int bb0[NW], bb1[NW], bb2[NW], bb3[NW];
  __shared__ float s_thr;
  __shared__ int s_apply;
  __shared__ int sbox[5];  // hs, he, ws, we, doit

  // ---- pass A: max + first argmax + min (the only HBM read of x) ----
  float vmax = -1.0f; int imax = 0x7fffffff; float vmin = 2.0f;
#pragma unroll
  for (int it = 0; it < ITER; ++it) {
    const int i = it * TPB + t;
    if (i < S4) {
      const float4 vv = xs[i];
      const int base = i * 4;
      if (vv.x > vmax) { vmax = vv.x; imax = base; }
      if (vv.y > vmax) { vmax = vv.y; imax = base + 1; }
      if (vv.z > vmax) { vmax = vv.z; imax = base + 2; }
      if (vv.w > vmax) { vmax = vv.w; imax = base + 3; }
      vmin = fminf(vmin, fminf(fminf(vv.x, vv.y), fminf(vv.z, vv.w)));
    }
  }
  for (int off = 32; off; off >>= 1) {
    float v2 = __shfl_xor(vmax, off);
    int   i2 = __shfl_xor(imax, off);
    float n2 = __shfl_xor(vmin, off);
    if (v2 > vmax || (v2 == vmax && i2 < imax)) { vmax = v2; imax = i2; }
    vmin = fminf(vmin, n2);
  }
  if (lane == 0) { pmax[wid] = vmax; pidx[wid] = imax; pmin[wid] = vmin; }
  __syncthreads();
  if (t == 0) {
    float mx = pmax[0]; int ix = pidx[0]; float mn = pmin[0];
    for (int wI = 1; wI < NW; ++wI) {
      if (pmax[wI] > mx || (pmax[wI] == mx && pidx[wI] < ix)) { mx = pmax[wI]; ix = pidx[wI]; }
      mn = fminf(mn, pmin[wI]);
    }
    // thr = mx - (mx - mn) * factor  -- no fma contraction (match XLA)
    s_thr = __fsub_rn(mx, __fmul_rn(__fsub_rn(mx, mn), factor));
    pidx[0] = ix;  // stash global argmax
    // apply_flag depends only on RNG -> decide now; half the samples skip pass B
    u32 kb0 = 0, kb1 = (u32)b; tf2x32(ks0, ks1, kb0, kb1);   // keys[b]
    u32 ka0 = 0, ka1 = 0; tf2x32(kb0, kb1, ka0, ka1);        // k_apply
    s_apply = (u01(rbits_scalar(ka0, ka1)) < 0.5f) ? 1 : 0;
    sbox[0] = 0; sbox[1] = 0; sbox[2] = 0; sbox[3] = 0; sbox[4] = 0;
  }
  __syncthreads();
  const float thr = s_thr;

  // ---- pass B: bbox of prop = x > thr (L3 re-read), only when apply ----
  if (s_apply) {
    int miny = HW, maxy = -1, minx = HW, maxx = -1;
#pragma unroll
    for (int it = 0; it < ITER; ++it) {
      const int i = it * TPB + t;
      if (i < S4) {
        const float4 vv = xs[i];
        const int base = i * 4;
        const int y = base / HW, xc = base % HW;  // 224%4==0 -> same row
        bool p0 = vv.x > thr, p1 = vv.y > thr, p2 = vv.z > thr, p3 = vv.w > thr;
        if (p0 | p1 | p2 | p3) { miny = min(miny, y); maxy = max(maxy, y); }
        if (p0) { minx = min(minx, xc);     maxx = max(maxx, xc); }
        if (p1) { minx = min(minx, xc + 1); maxx = max(maxx, xc + 1); }
        if (p2) { minx = min(minx, xc + 2); maxx = max(maxx, xc + 2); }
        if (p3) { minx = min(minx, xc + 3); maxx = max(maxx, xc + 3); }
      }
    }
    for (int off = 32; off; off >>= 1) {
      miny = min(miny, __shfl_xor(miny, off));
      maxy = max(maxy, __shfl_xor(maxy, off));
      minx = min(minx, __shfl_xor(minx, off));
      maxx = max(maxx, __shfl_xor(maxx, off));
    }
    if (lane == 0) { bb0[wid] = miny; bb1[wid] = maxy; bb2[wid] = minx; bb3[wid] = maxx; }
    __syncthreads();
    if (t == 0) {
      int mny = bb0[0], mxy = bb1[0], mnx = bb2[0], mxx = bb3[0];
      for (int wI = 1; wI < NW; ++wI) {
        mny = min(mny, bb0[wI]); mxy = max(mxy, bb1[wI]);
        mnx = min(mnx, bb2[wI]); mxx = max(mxx, bb3[wI]);
      }
      bool any = (mxy >= 0);
      int mh2 = (mxy - mny) / 2;
      int mw2 = (mxx - mnx) / 2;
      bool valid = any && (mh2 > 4) && (mw2 > 4);

      u32 kb0 = 0, kb1 = (u32)b; tf2x32(ks0, ks1, kb0, kb1);   // keys[b]
      u32 kh0 = 0, kh1 = 1; tf2x32(kb0, kb1, kh0, kh1);        // k_h
      u32 kw0 = 0, kw1 = 2; tf2x32(kb0, kb1, kw0, kw1);        // k_w
      float uh = u01(rbits_scalar(kh0, kh1));
      float uw = u01(rbits_scalar(kw0, kw1));

      int c = pidx[0], cy = c / HW, cx = c % HW;
      int h = 4 + (int)(uh * (float)max(mh2 - 4, 1));
      int w = 4 + (int)(uw * (float)max(mw2 - 4, 1));
      sbox[0] = max(cy - h, 0); sbox[1] = min(cy + h, HW);
      sbox[2] = max(cx - w, 0); sbox[3] = min(cx + w, HW);
      sbox[4] = valid ? 1 : 0;
    }
    __syncthreads();
  }
  const int hs = sbox[0], he = sbox[1], wss = sbox[2], wee = sbox[3];
  const int doit = sbox[4];
  const u32 eoff = (u32)b * (u32)S;

  // ---- pass C: write out/mask (L3 re-read of x); defer threefry ----
  unsigned long long need = 0ull;     // bit (it*4+j): element needs RNG
#pragma unroll
  for (int it = 0; it < ITER; ++it) {
    const int i = it * TPB + t;
    if (i < S4) {
      const int base = i * 4;
      const int y = base / HW, x0 = base % HW;
      const float4 vv = xs[i];
      const bool yin = doit && (y > hs) && (y < he) && (y > 0);
      float o[4], m[4];
#pragma unroll
      for (int j = 0; j < 4; ++j) {
        const float val = (j == 0) ? vv.x : (j == 1) ? vv.y : (j == 2) ? vv.z : vv.w;
        // inp = 0.6*x + 0.2 -- no fma contraction
        const float inp = __fadd_rn(__fmul_rn(0.6f, val), 0.2f);
        const int xx = x0 + j;
        const bool mz = yin && (val > thr) && (xx > wss) && (xx < wee) && (xx > 0);
        m[j] = mz ? 0.0f : 1.0f;
        o[j] = inp;                     // provisional; rare path may zero it
        if (mz) need |= 1ull << (it * 4 + j);
      }
      os[i] = make_float4(o[0], o[1], o[2], o[3]);
      ms[i] = make_float4(m[0], m[1], m[2], m[3]);
    }
  }

  // rare path: erased elements only — bernoulli via threefry, zero the drops
  while (need) {
    const int bit = __ffsll((unsigned long long)need) - 1;
    need &= need - 1;
    const int it = bit >> 2, j = bit & 3;
    const int base = (it * TPB + t) * 4 + j;
    const float val = ((const float*)xs)[base];          // L2/L3 hit
    const float inp = __fadd_rn(__fmul_rn(0.6f, val), 0.2f);
    const float kp  = fminf(fmaxf(__fsub_rn(1.0f, inp), 0.0f), 1.0f);
    u32 c0 = 0u, c1 = eoff + (u32)base;
    tf2x32(kn0, kn1, c0, c1);
    if (!(u01(c0 ^ c1) < kp))
      ((float*)os)[base] = 0.0f;                          // inp * 0
  }
}

// ---------------------------------------------------------------------------
extern "C" void kernel_launch(void* const* d_in, const int* in_sizes, int n_in,
                              void* d_out, int out_size, void* d_ws, size_t ws_size,
                              hipStream_t stream) {
  const float* x = (const float*)d_in[0];
  float* out = (float*)d_out;

  // host-side key derivation: root = key(42) = (0,42)
  u32 kf0 = 0, kf1 = 0; tf2x32(0u, 42u, kf0, kf1);   // k_factor = split[0]
  u32 ks0 = 0, ks1 = 1; tf2x32(0u, 42u, ks0, ks1);   // k_samples = split[1]
  u32 kn0 = 0, kn1 = 2; tf2x32(0u, 42u, kn0, kn1);   // k_noise  = split[2]
  float factor = fmaxf(0.0f, u01(rbits_scalar(kf0, kf1)) * 0.5f);

  hipLaunchKernelGGL(k_fused, dim3(BATCH), dim3(TPB), 0, stream,
                     x, out, factor, ks0, ks1, kn0, kn1);
}

// Round 5
// 83.564 us; speedup vs baseline: 1.3271x; 1.3271x over previous
//
#include <hip/hip_runtime.h>
#include <cstdint>

typedef unsigned int u32;
typedef float vf4 __attribute__((ext_vector_type(4)));   // builtin-friendly float4

// ---------------------------------------------------------------------------
// Threefry-2x32 (20 rounds) — validated bit-exact vs JAX in round 1
// (jax_threefry_partitionable=True semantics).
//   split(key, n)[i]           = threefry2x32(key, (0, i))
//   random_bits(key,32,shape)e = r0 ^ r1 of threefry2x32(key, (0, e))
// ---------------------------------------------------------------------------
#define TF_R4(a,b,r1,r2,r3,r4) \
  a += b; b = (b<<r1)|(b>>(32-r1)); b ^= a; \
  a += b; b = (b<<r2)|(b>>(32-r2)); b ^= a; \
  a += b; b = (b<<r3)|(b>>(32-r3)); b ^= a; \
  a += b; b = (b<<r4)|(b>>(32-r4)); b ^= a;

__host__ __device__ inline void tf2x32(u32 k0, u32 k1, u32& x0, u32& x1) {
  const u32 k2 = k0 ^ k1 ^ 0x1BD11BDAu;
  u32 a = x0 + k0, b = x1 + k1;
  TF_R4(a,b,13,15,26,6)   a += k1; b += k2 + 1u;
  TF_R4(a,b,17,29,16,24)  a += k2; b += k0 + 2u;
  TF_R4(a,b,13,15,26,6)   a += k0; b += k1 + 3u;
  TF_R4(a,b,17,29,16,24)  a += k1; b += k2 + 4u;
  TF_R4(a,b,13,15,26,6)   a += k2; b += k0 + 5u;
  x0 = a; x1 = b;
}

__host__ __device__ inline float u01(u32 bits) {
  union { u32 u; float f; } c; c.u = (bits >> 9) | 0x3f800000u;
  return c.f - 1.0f;
}
__host__ __device__ inline u32 rbits_scalar(u32 k0, u32 k1) {
  u32 a = 0, b = 0; tf2x32(k0, k1, a, b); return a ^ b;
}

// problem constants
#define BATCH   512
#define HW      224
#define S       50176     /* 224*224 */
#define S4      12544     /* S/4 = float4 per sample */
#define NTOT    25690112  /* 512*50176 */
#define Q4      3136      /* float4 per quarter-sample */
#define APB     49        /* k_apply blocks per sample: S4/256 */

struct SP { float thr; int hs, he, wss, wee, doit; int pad0, pad1; };
// ws layout: [0, 16384) SP[512]; [16384, ...) partials u32[2048*3]

// ---------------------------------------------------------------------------
// Kernel 1: quarter-sample partial max / first-argmax / min. Plain stores,
// no atomics, no ws init needed. 2048 blocks -> full occupancy, pure stream.
// ---------------------------------------------------------------------------
__global__ __launch_bounds__(256) void k_stats(const float* __restrict__ x,
                                               u32* __restrict__ part) {
  const int bid = blockIdx.x;
  const int b = bid >> 2, q = bid & 3;
  const int t = threadIdx.x;
  const int lane = t & 63, wid = t >> 6;
  const float4* __restrict__ xs = (const float4*)(x + (size_t)b * S);
  const int start = q * Q4, limit = start + Q4;

  float vmax = -1.0f; int imax = 0x7fffffff; float vmin = 2.0f;
#pragma unroll
  for (int it = 0; it < 13; ++it) {
    const int i = start + it * 256 + t;
    if (i < limit) {
      const float4 vv = xs[i];
      const int base = i * 4;
      if (vv.x > vmax) { vmax = vv.x; imax = base; }
      if (vv.y > vmax) { vmax = vv.y; imax = base + 1; }
      if (vv.z > vmax) { vmax = vv.z; imax = base + 2; }
      if (vv.w > vmax) { vmax = vv.w; imax = base + 3; }
      vmin = fminf(vmin, fminf(fminf(vv.x, vv.y), fminf(vv.z, vv.w)));
    }
  }
  for (int off = 32; off; off >>= 1) {
    float v2 = __shfl_xor(vmax, off);
    int   i2 = __shfl_xor(imax, off);
    float n2 = __shfl_xor(vmin, off);
    if (v2 > vmax || (v2 == vmax && i2 < imax)) { vmax = v2; imax = i2; }
    vmin = fminf(vmin, n2);
  }
  __shared__ float pm[4]; __shared__ int pi[4]; __shared__ float pn[4];
  if (lane == 0) { pm[wid] = vmax; pi[wid] = imax; pn[wid] = vmin; }
  __syncthreads();
  if (t == 0) {
    float mx = pm[0]; int ix = pi[0]; float mn = pn[0];
    for (int wI = 1; wI < 4; ++wI) {
      if (pm[wI] > mx || (pm[wI] == mx && pi[wI] < ix)) { mx = pm[wI]; ix = pi[wI]; }
      mn = fminf(mn, pn[wI]);
    }
    part[bid * 3 + 0] = __float_as_uint(mx);
    part[bid * 3 + 1] = (u32)ix;
    part[bid * 3 + 2] = __float_as_uint(mn);
  }
}

// ---------------------------------------------------------------------------
// Kernel 2: per-sample params. Combine partials, RNG apply flag; if apply,
// bbox scan of prop = x > thr (x still L2/L3-resident: nothing wrote since).
// ---------------------------------------------------------------------------
#define BTPB 1024
#define BNW  16
__global__ __launch_bounds__(BTPB) void k_box(const float* __restrict__ x,
                                              const u32* __restrict__ part,
                                              SP* __restrict__ sp,
                                              float factor, u32 ks0, u32 ks1) {
  const int b = blockIdx.x;
  const int t = threadIdx.x;
  const int lane = t & 63, wid = t >> 6;

  __shared__ float s_thr; __shared__ int s_apply; __shared__ int s_ix;
  if (t == 0) {
    float mx = -1.0f, mn = 2.0f; int ix = 0x7fffffff;
    for (int q = 0; q < 4; ++q) {
      const float v = __uint_as_float(part[(b * 4 + q) * 3 + 0]);
      const int   i = (int)part[(b * 4 + q) * 3 + 1];
      const float n = __uint_as_float(part[(b * 4 + q) * 3 + 2]);
      if (v > mx) { mx = v; ix = i; }   // indices increase with q -> first-max kept
      mn = fminf(mn, n);
    }
    // thr = mx - (mx - mn) * factor  -- no fma contraction (match XLA)
    s_thr = __fsub_rn(mx, __fmul_rn(__fsub_rn(mx, mn), factor));
    s_ix = ix;
    u32 kb0 = 0, kb1 = (u32)b; tf2x32(ks0, ks1, kb0, kb1);   // keys[b]
    u32 ka0 = 0, ka1 = 0; tf2x32(kb0, kb1, ka0, ka1);        // k_apply
    s_apply = (u01(rbits_scalar(ka0, ka1)) < 0.5f) ? 1 : 0;
  }
  __syncthreads();
  const float thr = s_thr;

  if (!s_apply) {
    if (t == 0) {
      SP p; p.thr = thr; p.hs = 0; p.he = 0; p.wss = 0; p.wee = 0;
      p.doit = 0; p.pad0 = 0; p.pad1 = 0;
      sp[b] = p;
    }
    return;
  }

  const float4* __restrict__ xs = (const float4*)(x + (size_t)b * S);
  int miny = HW, maxy = -1, minx = HW, maxx = -1;
#pragma unroll
  for (int it = 0; it < 13; ++it) {
    const int i = it * BTPB + t;
    if (i < S4) {
      const float4 vv = xs[i];
      const int base = i * 4;
      const int y = base / HW, xc = base % HW;  // 224%4==0 -> same row
      bool p0 = vv.x > thr, p1 = vv.y > thr, p2 = vv.z > thr, p3 = vv.w > thr;
      if (p0 | p1 | p2 | p3) { miny = min(miny, y); maxy = max(maxy, y); }
      if (p0) { minx = min(minx, xc);     maxx = max(maxx, xc); }
      if (p1) { minx = min(minx, xc + 1); maxx = max(maxx, xc + 1); }
      if (p2) { minx = min(minx, xc + 2); maxx = max(maxx, xc + 2); }
      if (p3) { minx = min(minx, xc + 3); maxx = max(maxx, xc + 3); }
    }
  }
  for (int off = 32; off; off >>= 1) {
    miny = min(miny, __shfl_xor(miny, off));
    maxy = max(maxy, __shfl_xor(maxy, off));
    minx = min(minx, __shfl_xor(minx, off));
    maxx = max(maxx, __shfl_xor(maxx, off));
  }
  __shared__ int bb0[BNW], bb1[BNW], bb2[BNW], bb3[BNW];
  if (lane == 0) { bb0[wid] = miny; bb1[wid] = maxy; bb2[wid] = minx; bb3[wid] = maxx; }
  __syncthreads();
  if (t == 0) {
    int mny = bb0[0], mxy = bb1[0], mnx = bb2[0], mxx = bb3[0];
    for (int wI = 1; wI < BNW; ++wI) {
      mny = min(mny, bb0[wI]); mxy = max(mxy, bb1[wI]);
      mnx = min(mnx, bb2[wI]); mxx = max(mxx, bb3[wI]);
    }
    bool any = (mxy >= 0);
    int mh2 = (mxy - mny) / 2;
    int mw2 = (mxx - mnx) / 2;
    bool valid = any && (mh2 > 4) && (mw2 > 4);

    u32 kb0 = 0, kb1 = (u32)b; tf2x32(ks0, ks1, kb0, kb1);   // keys[b]
    u32 kh0 = 0, kh1 = 1; tf2x32(kb0, kb1, kh0, kh1);        // k_h
    u32 kw0 = 0, kw1 = 2; tf2x32(kb0, kb1, kw0, kw1);        // k_w
    float uh = u01(rbits_scalar(kh0, kh1));
    float uw = u01(rbits_scalar(kw0, kw1));

    int c = s_ix, cy = c / HW, cx = c % HW;
    int h = 4 + (int)(uh * (float)max(mh2 - 4, 1));
    int w = 4 + (int)(uw * (float)max(mw2 - 4, 1));
    SP p;
    p.thr = thr;
    p.hs = max(cy - h, 0); p.he = min(cy + h, HW);
    p.wss = max(cx - w, 0); p.wee = min(cx + w, HW);
    p.doit = valid ? 1 : 0;
    p.pad0 = 0; p.pad1 = 0;
    sp[b] = p;
  }
}

// ---------------------------------------------------------------------------
// Kernel 3: elementwise apply. One block = 256 consecutive float4 of one
// sample. Bernoulli threefry computed INLINE only for erased lanes (single
// touch per output line; no post-pass RMW). Nontemporal streaming stores.
// ---------------------------------------------------------------------------
__global__ __launch_bounds__(256) void k_apply(const float* __restrict__ x,
                                               const SP* __restrict__ sp,
                                               float* __restrict__ out,
                                               u32 kn0, u32 kn1) {
  const int bid = blockIdx.x;
  const int b   = bid / APB;
  const int i   = (bid % APB) * 256 + threadIdx.x;   // float4 index in sample
  const SP p = sp[b];
  const vf4 vv = ((const vf4*)(x + (size_t)b * S))[i];
  vf4* __restrict__ os = (vf4*)(out + (size_t)b * S);
  vf4* __restrict__ ms = (vf4*)(out + (size_t)NTOT + (size_t)b * S);

  const int base = i * 4;
  const int y = base / HW, x0 = base % HW;
  const bool yin = p.doit && (y > p.hs) && (y < p.he) && (y > 0);
  const u32 eoff = (u32)b * (u32)S;

  vf4 o, m;
  int need = 0;
#pragma unroll
  for (int j = 0; j < 4; ++j) {
    const float val = vv[j];
    // inp = 0.6*x + 0.2 -- no fma contraction
    const float inp = __fadd_rn(__fmul_rn(0.6f, val), 0.2f);
    const int xx = x0 + j;
    const bool mz = yin && (val > p.thr) && (xx > p.wss) && (xx < p.wee) && (xx > 0);
    m[j] = mz ? 0.0f : 1.0f;
    o[j] = inp;
    if (mz) need |= 1 << j;
  }
  if (need) {
#pragma unroll
    for (int j = 0; j < 4; ++j) {
      if (need & (1 << j)) {
        const float kp = fminf(fmaxf(__fsub_rn(1.0f, o[j]), 0.0f), 1.0f);
        u32 c0 = 0u, c1 = eoff + (u32)(base + j);
        tf2x32(kn0, kn1, c0, c1);
        if (!(u01(c0 ^ c1) < kp)) o[j] = 0.0f;   // inp * 0
      }
    }
  }
  __builtin_nontemporal_store(o, &os[i]);
  __builtin_nontemporal_store(m, &ms[i]);
}

// ---------------------------------------------------------------------------
extern "C" void kernel_launch(void* const* d_in, const int* in_sizes, int n_in,
                              void* d_out, int out_size, void* d_ws, size_t ws_size,
                              hipStream_t stream) {
  const float* x = (const float*)d_in[0];
  float* out = (float*)d_out;
  SP*  sp   = (SP*)d_ws;
  u32* part = (u32*)((char*)d_ws + 16384);

  // host-side key derivation: root = key(42) = (0,42)
  u32 kf0 = 0, kf1 = 0; tf2x32(0u, 42u, kf0, kf1);   // k_factor = split[0]
  u32 ks0 = 0, ks1 = 1; tf2x32(0u, 42u, ks0, ks1);   // k_samples = split[1]
  u32 kn0 = 0, kn1 = 2; tf2x32(0u, 42u, kn0, kn1);   // k_noise  = split[2]
  float factor = fmaxf(0.0f, u01(rbits_scalar(kf0, kf1)) * 0.5f);

  hipLaunchKernelGGL(k_stats, dim3(BATCH * 4), dim3(256), 0, stream, x, part);
  hipLaunchKernelGGL(k_box,   dim3(BATCH), dim3(BTPB), 0, stream,
                     x, part, sp, factor, ks0, ks1);
  hipLaunchKernelGGL(k_apply, dim3(BATCH * APB), dim3(256), 0, stream,
                     x, sp, out, kn0, kn1);
}

// Round 6
// 72.830 us; speedup vs baseline: 1.5227x; 1.1474x over previous
//
#include <hip/hip_runtime.h>
#include <cstdint>

typedef unsigned int u32;
typedef float vf4 __attribute__((ext_vector_type(4)));   // builtin-friendly float4

// ---------------------------------------------------------------------------
// Threefry-2x32 (20 rounds) — validated bit-exact vs JAX in round 1
// (jax_threefry_partitionable=True semantics).
//   split(key, n)[i]           = threefry2x32(key, (0, i))
//   random_bits(key,32,shape)e = r0 ^ r1 of threefry2x32(key, (0, e))
// ---------------------------------------------------------------------------
#define TF_R4(a,b,r1,r2,r3,r4) \
  a += b; b = (b<<r1)|(b>>(32-r1)); b ^= a; \
  a += b; b = (b<<r2)|(b>>(32-r2)); b ^= a; \
  a += b; b = (b<<r3)|(b>>(32-r3)); b ^= a; \
  a += b; b = (b<<r4)|(b>>(32-r4)); b ^= a;

__host__ __device__ inline void tf2x32(u32 k0, u32 k1, u32& x0, u32& x1) {
  const u32 k2 = k0 ^ k1 ^ 0x1BD11BDAu;
  u32 a = x0 + k0, b = x1 + k1;
  TF_R4(a,b,13,15,26,6)   a += k1; b += k2 + 1u;
  TF_R4(a,b,17,29,16,24)  a += k2; b += k0 + 2u;
  TF_R4(a,b,13,15,26,6)   a += k0; b += k1 + 3u;
  TF_R4(a,b,17,29,16,24)  a += k1; b += k2 + 4u;
  TF_R4(a,b,13,15,26,6)   a += k2; b += k0 + 5u;
  x0 = a; x1 = b;
}

__host__ __device__ inline float u01(u32 bits) {
  union { u32 u; float f; } c; c.u = (bits >> 9) | 0x3f800000u;
  return c.f - 1.0f;
}
__host__ __device__ inline u32 rbits_scalar(u32 k0, u32 k1) {
  u32 a = 0, b = 0; tf2x32(k0, k1, a, b); return a ^ b;
}

// problem constants
#define BATCH   512
#define HW      224
#define S       50176     /* 224*224 */
#define S4      12544     /* S/4 = float4 per sample */
#define NTOT    25690112  /* 512*50176 */
#define APB     49        /* k_apply blocks per sample: S4/256 */
#define FSTR    1152      /* floats per sample in ws stats area (pad from 1132) */
// per-sample ws float layout:
//   [0,224)        rowmax[r]
//   [224,1120)     colmax quarter partials cm[q][224]
//   [1120,1132)    per-quarter stats {max, argmax-bits, min} x 4
// total ws: 16384 B (SP) + 512*1152*4 B = ~2.38 MB

struct SP { float thr; int hs, he, wss, wee, doit; int pad0, pad1; };

// ---------------------------------------------------------------------------
// Kernel 1: single pass over x. Block = one quarter (56 rows) of one sample.
// Wave layout: wave wv owns rows wv*14..wv*14+13; lane (<56) owns col4=lane.
//   - rowmax via 6-step shuffle reduce per row
//   - colmax accumulated per-lane in registers (4 floats), LDS-combined
//   - global max / first-argmax / min per quarter
// No atomics, no second pass over x anywhere in the pipeline.
// ---------------------------------------------------------------------------
__global__ __launch_bounds__(256) void k_stats(const float* __restrict__ x,
                                               float* __restrict__ fdata) {
  const int bid = blockIdx.x;
  const int b = bid >> 2, q = bid & 3;
  const int t = threadIdx.x;
  const int lane = t & 63, wv = t >> 6;
  const float* __restrict__ xs = x + (size_t)b * S;
  float* __restrict__ base = fdata + (size_t)b * FSTR;
  const bool act = lane < 56;

  vf4 cmax = (vf4){0.f, 0.f, 0.f, 0.f};       // x in [0,1) -> 0 is neutral
  float amax = -1.f; int aidx = 0x7fffffff; float amin = 2.f;

#pragma unroll
  for (int k = 0; k < 14; ++k) {
    const int r = q * 56 + wv * 14 + k;
    vf4 v = (vf4){-1.f, -1.f, -1.f, -1.f};    // idle lanes: neutral for max
    if (act) v = ((const vf4*)(xs + (size_t)r * HW))[lane];
    float rv = fmaxf(fmaxf(v[0], v[1]), fmaxf(v[2], v[3]));
    if (act) {
      cmax[0] = fmaxf(cmax[0], v[0]); cmax[1] = fmaxf(cmax[1], v[1]);
      cmax[2] = fmaxf(cmax[2], v[2]); cmax[3] = fmaxf(cmax[3], v[3]);
      const int fb = r * HW + lane * 4;
      if (v[0] > amax) { amax = v[0]; aidx = fb; }
      if (v[1] > amax) { amax = v[1]; aidx = fb + 1; }
      if (v[2] > amax) { amax = v[2]; aidx = fb + 2; }
      if (v[3] > amax) { amax = v[3]; aidx = fb + 3; }
      amin = fminf(amin, fminf(fminf(v[0], v[1]), fminf(v[2], v[3])));
    }
    for (int off = 32; off; off >>= 1) rv = fmaxf(rv, __shfl_xor(rv, off));
    if (lane == 0) base[r] = rv;              // rowmax
  }
  // wave reduce argmax (first) / min
  for (int off = 32; off; off >>= 1) {
    float v2 = __shfl_xor(amax, off);
    int   i2 = __shfl_xor(aidx, off);
    float n2 = __shfl_xor(amin, off);
    if (v2 > amax || (v2 == amax && i2 < aidx)) { amax = v2; aidx = i2; }
    amin = fminf(amin, n2);
  }
  __shared__ vf4 cmw[4][56];
  __shared__ float wmx[4]; __shared__ int wix[4]; __shared__ float wmn[4];
  if (act) cmw[wv][lane] = cmax;
  if (lane == 0) { wmx[wv] = amax; wix[wv] = aidx; wmn[wv] = amin; }
  __syncthreads();
  if (t < 56) {
    vf4 a = cmw[0][t], c1 = cmw[1][t], c2 = cmw[2][t], c3 = cmw[3][t];
    vf4 m;
    m[0] = fmaxf(fmaxf(a[0], c1[0]), fmaxf(c2[0], c3[0]));
    m[1] = fmaxf(fmaxf(a[1], c1[1]), fmaxf(c2[1], c3[1]));
    m[2] = fmaxf(fmaxf(a[2], c1[2]), fmaxf(c2[2], c3[2]));
    m[3] = fmaxf(fmaxf(a[3], c1[3]), fmaxf(c2[3], c3[3]));
    ((vf4*)(base + 224 + q * 224))[t] = m;    // colmax quarter partial
  }
  if (t == 0) {
    float mx = wmx[0]; int ix = wix[0]; float mn = wmn[0];
    for (int wI = 1; wI < 4; ++wI) {
      if (wmx[wI] > mx || (wmx[wI] == mx && wix[wI] < ix)) { mx = wmx[wI]; ix = wix[wI]; }
      mn = fminf(mn, wmn[wI]);
    }
    base[1120 + q * 3 + 0] = mx;
    base[1120 + q * 3 + 1] = __int_as_float(ix);
    base[1120 + q * 3 + 2] = mn;
  }
}

// ---------------------------------------------------------------------------
// Kernel 2: per-sample params from ws ONLY (no x access). One block/sample.
// bbox from rowmax/colmax: miny = min{r : rowmax[r] > thr}, etc.
// ---------------------------------------------------------------------------
__global__ __launch_bounds__(256) void k_box(const float* __restrict__ fdata,
                                             SP* __restrict__ sp,
                                             float factor, u32 ks0, u32 ks1) {
  const int b = blockIdx.x;
  const int t = threadIdx.x;
  const int lane = t & 63, wv = t >> 6;
  const float* __restrict__ base = fdata + (size_t)b * FSTR;

  // combine quarter stats (redundant per thread; broadcast loads)
  float mx = -1.f; int ix = 0x7fffffff; float mn = 2.f;
#pragma unroll
  for (int q = 0; q < 4; ++q) {
    const float v = base[1120 + q * 3 + 0];
    const int   i = __float_as_int(base[1120 + q * 3 + 1]);
    const float n = base[1120 + q * 3 + 2];
    if (v > mx || (v == mx && i < ix)) { mx = v; ix = i; }
    mn = fminf(mn, n);
  }
  // thr = mx - (mx - mn) * factor -- no fma contraction (match XLA)
  const float thr = __fsub_rn(mx, __fmul_rn(__fsub_rn(mx, mn), factor));

  u32 kb0 = 0, kb1 = (u32)b; tf2x32(ks0, ks1, kb0, kb1);   // keys[b]
  u32 ka0 = 0, ka1 = 0; tf2x32(kb0, kb1, ka0, ka1);        // k_apply
  const bool apply = u01(rbits_scalar(ka0, ka1)) < 0.5f;
  if (!apply) {
    if (t == 0) {
      SP p; p.thr = thr; p.hs = 0; p.he = 0; p.wss = 0; p.wee = 0;
      p.doit = 0; p.pad0 = 0; p.pad1 = 0;
      sp[b] = p;
    }
    return;
  }

  int miny = HW, maxy = -1, minx = HW, maxx = -1;
  if (t < HW) {
    if (base[t] > thr) { miny = t; maxy = t; }           // row flag
    const float c0 = base[224 + t],       c1 = base[224 + 224 + t];
    const float c2 = base[224 + 448 + t], c3 = base[224 + 672 + t];
    if (fmaxf(fmaxf(c0, c1), fmaxf(c2, c3)) > thr) { minx = t; maxx = t; }
  }
  for (int off = 32; off; off >>= 1) {
    miny = min(miny, __shfl_xor(miny, off));
    maxy = max(maxy, __shfl_xor(maxy, off));
    minx = min(minx, __shfl_xor(minx, off));
    maxx = max(maxx, __shfl_xor(maxx, off));
  }
  __shared__ int r0[4], r1[4], r2[4], r3[4];
  if (lane == 0) { r0[wv] = miny; r1[wv] = maxy; r2[wv] = minx; r3[wv] = maxx; }
  __syncthreads();
  if (t == 0) {
    int mny = r0[0], mxy = r1[0], mnx = r2[0], mxx = r3[0];
    for (int wI = 1; wI < 4; ++wI) {
      mny = min(mny, r0[wI]); mxy = max(mxy, r1[wI]);
      mnx = min(mnx, r2[wI]); mxx = max(mxx, r3[wI]);
    }
    const bool any = (mxy >= 0);
    const int mh2 = (mxy - mny) / 2;
    const int mw2 = (mxx - mnx) / 2;
    const bool valid = any && (mh2 > 4) && (mw2 > 4);

    u32 kh0 = 0, kh1 = 1; tf2x32(kb0, kb1, kh0, kh1);    // k_h
    u32 kw0 = 0, kw1 = 2; tf2x32(kb0, kb1, kw0, kw1);    // k_w
    const float uh = u01(rbits_scalar(kh0, kh1));
    const float uw = u01(rbits_scalar(kw0, kw1));

    const int cy = ix / HW, cx = ix % HW;
    const int h = 4 + (int)(uh * (float)max(mh2 - 4, 1));
    const int w = 4 + (int)(uw * (float)max(mw2 - 4, 1));
    SP p;
    p.thr = thr;
    p.hs = max(cy - h, 0); p.he = min(cy + h, HW);
    p.wss = max(cx - w, 0); p.wee = min(cx + w, HW);
    p.doit = valid ? 1 : 0;
    p.pad0 = 0; p.pad1 = 0;
    sp[b] = p;
  }
}

// ---------------------------------------------------------------------------
// Kernel 3: elementwise apply (unchanged from round 5). One block = 256
// consecutive float4 of one sample; inline threefry only for erased lanes;
// nontemporal streaming stores.
// ---------------------------------------------------------------------------
__global__ __launch_bounds__(256) void k_apply(const float* __restrict__ x,
                                               const SP* __restrict__ sp,
                                               float* __restrict__ out,
                                               u32 kn0, u32 kn1) {
  const int bid = blockIdx.x;
  const int b   = bid / APB;
  const int i   = (bid % APB) * 256 + threadIdx.x;   // float4 index in sample
  const SP p = sp[b];
  const vf4 vv = ((const vf4*)(x + (size_t)b * S))[i];
  vf4* __restrict__ os = (vf4*)(out + (size_t)b * S);
  vf4* __restrict__ ms = (vf4*)(out + (size_t)NTOT + (size_t)b * S);

  const int base = i * 4;
  const int y = base / HW, x0 = base % HW;
  const bool yin = p.doit && (y > p.hs) && (y < p.he) && (y > 0);
  const u32 eoff = (u32)b * (u32)S;

  vf4 o, m;
  int need = 0;
#pragma unroll
  for (int j = 0; j < 4; ++j) {
    const float val = vv[j];
    // inp = 0.6*x + 0.2 -- no fma contraction
    const float inp = __fadd_rn(__fmul_rn(0.6f, val), 0.2f);
    const int xx = x0 + j;
    const bool mz = yin && (val > p.thr) && (xx > p.wss) && (xx < p.wee) && (xx > 0);
    m[j] = mz ? 0.0f : 1.0f;
    o[j] = inp;
    if (mz) need |= 1 << j;
  }
  if (need) {
#pragma unroll
    for (int j = 0; j < 4; ++j) {
      if (need & (1 << j)) {
        const float kp = fminf(fmaxf(__fsub_rn(1.0f, o[j]), 0.0f), 1.0f);
        u32 c0 = 0u, c1 = eoff + (u32)(base + j);
        tf2x32(kn0, kn1, c0, c1);
        if (!(u01(c0 ^ c1) < kp)) o[j] = 0.0f;   // inp * 0
      }
    }
  }
  __builtin_nontemporal_store(o, &os[i]);
  __builtin_nontemporal_store(m, &ms[i]);
}

// ---------------------------------------------------------------------------
extern "C" void kernel_launch(void* const* d_in, const int* in_sizes, int n_in,
                              void* d_out, int out_size, void* d_ws, size_t ws_size,
                              hipStream_t stream) {
  const float* x = (const float*)d_in[0];
  float* out = (float*)d_out;
  SP*    sp    = (SP*)d_ws;
  float* fdata = (float*)((char*)d_ws + 16384);

  // host-side key derivation: root = key(42) = (0,42)
  u32 kf0 = 0, kf1 = 0; tf2x32(0u, 42u, kf0, kf1);   // k_factor = split[0]
  u32 ks0 = 0, ks1 = 1; tf2x32(0u, 42u, ks0, ks1);   // k_samples = split[1]
  u32 kn0 = 0, kn1 = 2; tf2x32(0u, 42u, kn0, kn1);   // k_noise  = split[2]
  float factor = fmaxf(0.0f, u01(rbits_scalar(kf0, kf1)) * 0.5f);

  hipLaunchKernelGGL(k_stats, dim3(BATCH * 4), dim3(256), 0, stream, x, fdata);
  hipLaunchKernelGGL(k_box,   dim3(BATCH), dim3(256), 0, stream,
                     fdata, sp, factor, ks0, ks1);
  hipLaunchKernelGGL(k_apply, dim3(BATCH * APB), dim3(256), 0, stream,
                     x, sp, out, kn0, kn1);
}